// Round 5
// baseline (68.916 us; speedup 1.0000x reference)
//
#include <hip/hip_runtime.h>

// Bahdanau additive attention, f32. B=8, TQ=128, TK=512, NIN=512, H=128, NV=512.
// out = [context (B*TQ*NV), attn (B*TQ*TK)] f32.

#define B_    8
#define TQ_   128
#define TK_   512
#define NIN_  512
#define H_    128
#define NV_   512
#define NQR   (B_*TQ_)           // 1024 query rows
#define NROWS (NQR + B_*TK_)     // 5120 total projected rows

#define C2_   2.8853900817779268f   // 2*log2(e)
#define L2E_  1.4426950408889634f

__device__ __forceinline__ float fexp2(float x){ return __builtin_amdgcn_exp2f(x); }
__device__ __forceinline__ float frcp (float x){ return __builtin_amdgcn_rcpf(x); }

// ---------------------------------------------------------------- proj ----
// psum[s][row][h] = A[row, ks:ke) . W[h, ks:ke)
// grid (NROWS/16, 4): tile 16 rows x 128 h, K-chunk 32, kper=128.
__global__ __launch_bounds__(256, 5) void proj_kernel(
        const float* __restrict__ query, const float* __restrict__ keys,
        const float* __restrict__ Wq, const float* __restrict__ Wk,
        float* __restrict__ psum, int kper) {
    __shared__ float at[32][18];     // [kk][row], 16 rows
    __shared__ float wt[32][132];    // [kk][h]
    const int tid = threadIdx.x;
    const int r0  = blockIdx.x * 16;
    const float* in; const float* W;
    if (r0 < NQR) { in = query + (size_t)r0 * NIN_;         W = Wq; }
    else          { in = keys  + (size_t)(r0 - NQR) * NIN_; W = Wk; }

    const int r2 = (tid >> 5) * 2;       // 2 rows
    const int h4 = (tid & 31) * 4;       // 4 h
    const int ar  = tid >> 4;            // A-stage row 0..15
    const int ak2 = (tid & 15) * 2;      // A-stage k pair
    const int wr  = tid >> 3;            // W-stage h row 0..31 (+32p)
    const int wkq = (tid & 7) * 4;       // W-stage k quad
    const int kb0 = blockIdx.y * kper;
    const int nc  = kper >> 5;

    const float* pA  = in + ar * NIN_ + kb0 + ak2;
    const float* pW0 = W + (wr     ) * NIN_ + kb0 + wkq;
    const float* pW1 = W + (wr + 32) * NIN_ + kb0 + wkq;
    const float* pW2 = W + (wr + 64) * NIN_ + kb0 + wkq;
    const float* pW3 = W + (wr + 96) * NIN_ + kb0 + wkq;

    float2 af  = *(const float2*)pA;
    float4 wf0 = *(const float4*)pW0;
    float4 wf1 = *(const float4*)pW1;
    float4 wf2 = *(const float4*)pW2;
    float4 wf3 = *(const float4*)pW3;

    float acc[2][4] = {{0.f,0.f,0.f,0.f},{0.f,0.f,0.f,0.f}};

    for (int c = 0; c < nc; ++c) {
        __syncthreads();
        at[ak2+0][ar] = af.x;  at[ak2+1][ar] = af.y;
        wt[wkq+0][wr   ] = wf0.x; wt[wkq+1][wr   ] = wf0.y;
        wt[wkq+2][wr   ] = wf0.z; wt[wkq+3][wr   ] = wf0.w;
        wt[wkq+0][wr+32] = wf1.x; wt[wkq+1][wr+32] = wf1.y;
        wt[wkq+2][wr+32] = wf1.z; wt[wkq+3][wr+32] = wf1.w;
        wt[wkq+0][wr+64] = wf2.x; wt[wkq+1][wr+64] = wf2.y;
        wt[wkq+2][wr+64] = wf2.z; wt[wkq+3][wr+64] = wf2.w;
        wt[wkq+0][wr+96] = wf3.x; wt[wkq+1][wr+96] = wf3.y;
        wt[wkq+2][wr+96] = wf3.z; wt[wkq+3][wr+96] = wf3.w;
        __syncthreads();
        if (c + 1 < nc) {
            pA += 32; pW0 += 32; pW1 += 32; pW2 += 32; pW3 += 32;
            af  = *(const float2*)pA;
            wf0 = *(const float4*)pW0; wf1 = *(const float4*)pW1;
            wf2 = *(const float4*)pW2; wf3 = *(const float4*)pW3;
        }
#pragma unroll 8
        for (int kk = 0; kk < 32; ++kk) {
            float2 a = *(const float2*)&at[kk][r2];
            float4 w = *(const float4*)&wt[kk][h4];
            acc[0][0] = fmaf(a.x, w.x, acc[0][0]);
            acc[0][1] = fmaf(a.x, w.y, acc[0][1]);
            acc[0][2] = fmaf(a.x, w.z, acc[0][2]);
            acc[0][3] = fmaf(a.x, w.w, acc[0][3]);
            acc[1][0] = fmaf(a.y, w.x, acc[1][0]);
            acc[1][1] = fmaf(a.y, w.y, acc[1][1]);
            acc[1][2] = fmaf(a.y, w.z, acc[1][2]);
            acc[1][3] = fmaf(a.y, w.w, acc[1][3]);
        }
    }

    float* op = psum + ((size_t)blockIdx.y * NROWS + r0) * H_;
#pragma unroll
    for (int i = 0; i < 2; ++i) {
        float4 o = {acc[i][0], acc[i][1], acc[i][2], acc[i][3]};
        *(float4*)&op[(r2 + i) * H_ + h4] = o;
    }
}

// -------------------------------------------------------------- reduce ----
// Per block: 16 rows. Sum 4 psum splits + bias.
// q-rows -> qp row-major. k-rows -> kpT[b][h][k] (transposed, *C2 folded).
__global__ __launch_bounds__(256, 4) void reduce_kernel(
        const float* __restrict__ psum, const float* __restrict__ bq,
        const float* __restrict__ bk, float* __restrict__ qp,
        float* __restrict__ kpT) {
    __shared__ float lt[128][17];
    const int tid = threadIdx.x;
    const int r0  = blockIdx.x * 16;
    const bool isq = (r0 < NQR);
    const float* bias = isq ? bq : bk;

#pragma unroll
    for (int p = 0; p < 2; ++p) {
        const int j = tid + p * 256;          // 0..511 over [16 rows][32 hq]
        const int row = j >> 5, hq = (j & 31) * 4;
        const float4 b4 = *(const float4*)&bias[hq];
        float4 s = b4;
#pragma unroll
        for (int sp = 0; sp < 4; ++sp) {
            float4 v = *(const float4*)&psum[((size_t)sp * NROWS + r0 + row) * H_ + hq];
            s.x += v.x; s.y += v.y; s.z += v.z; s.w += v.w;
        }
        if (isq) {
            *(float4*)&qp[(size_t)(r0 + row) * H_ + hq] = s;
        } else {
            lt[hq + 0][row] = s.x * C2_; lt[hq + 1][row] = s.y * C2_;
            lt[hq + 2][row] = s.z * C2_; lt[hq + 3][row] = s.w * C2_;
        }
    }
    if (!isq) {
        __syncthreads();
        const int b  = (r0 - NQR) >> 9;
        const int k0 = (r0 - NQR) & 511;
#pragma unroll
        for (int p = 0; p < 2; ++p) {
            const int j = tid + p * 256;      // 0..511 over [128 h][4 kq]
            const int h = j >> 2, kq = (j & 3) * 4;
            float4 o = {lt[h][kq], lt[h][kq + 1], lt[h][kq + 2], lt[h][kq + 3]};
            *(float4*)&kpT[((size_t)b * H_ + h) * TK_ + k0 + kq] = o;
        }
    }
}

// -------------------------------------------------------------- scores ----
// Per block: batch b, 2 q rows. Thread = (1 q, 4 k); k contiguous via kpT.
// score = bo + sumWo - 2*sum_h Wo_h/(e^(2x_h)+1)
__global__ __launch_bounds__(256, 4) void scores_kernel(
        const float* __restrict__ qp, const float* __restrict__ kpT,
        const float* __restrict__ Wo, const float* __restrict__ bo,
        float* __restrict__ out_attn) {
    __shared__ float qs2[2][H_];    // q_proj * C2
    __shared__ float w2[H_];        // -2 * Wo
    __shared__ float sc[2][TK_];

    const int tid = threadIdx.x;
    const int b   = blockIdx.y;
    const int q0  = blockIdx.x * 2;
    const int lane = tid & 63;

    qs2[tid >> 7][tid & 127] =
        qp[(b * TQ_ + q0 + (tid >> 7)) * H_ + (tid & 127)] * C2_;
    if (tid < H_) w2[tid] = Wo[tid] * -2.0f;
    __syncthreads();

    float sw = w2[lane] + w2[lane + 64];
#pragma unroll
    for (int m = 1; m < 64; m <<= 1) sw += __shfl_xor(sw, m);
    const float sbase = bo[0] - 0.5f * sw;

    const int k4 = (tid & 127) * 4;        // 4 k's per thread
    const int qi = tid >> 7;               // q row 0/1
    const float* pk = kpT + (size_t)b * H_ * TK_ + k4;
    float a0 = 0.f, a1 = 0.f, a2 = 0.f, a3 = 0.f;
#pragma unroll 4
    for (int h = 0; h < H_; ++h) {
        float4 kv = *(const float4*)pk;
        pk += TK_;
        const float qv = qs2[qi][h];
        const float wv = w2[h];
        a0 = fmaf(wv, frcp(fexp2(qv + kv.x) + 1.0f), a0);
        a1 = fmaf(wv, frcp(fexp2(qv + kv.y) + 1.0f), a1);
        a2 = fmaf(wv, frcp(fexp2(qv + kv.z) + 1.0f), a2);
        a3 = fmaf(wv, frcp(fexp2(qv + kv.w) + 1.0f), a3);
    }
    float4 sv = {a0 + sbase, a1 + sbase, a2 + sbase, a3 + sbase};
    *(float4*)&sc[qi][k4] = sv;
    __syncthreads();

    // softmax: waves 0,1 -> rows 0,1 (8 scores per lane); waves 2,3 idle
    const int w = tid >> 6;
    if (w < 2) {
        float4 sA = *(const float4*)&sc[w][lane * 8];
        float4 sB = *(const float4*)&sc[w][lane * 8 + 4];
        float m = fmaxf(fmaxf(fmaxf(sA.x, sA.y), fmaxf(sA.z, sA.w)),
                        fmaxf(fmaxf(sB.x, sB.y), fmaxf(sB.z, sB.w)));
#pragma unroll
        for (int mask = 1; mask < 64; mask <<= 1) m = fmaxf(m, __shfl_xor(m, mask));
        float4 eA, eB;
        eA.x = fexp2((sA.x - m) * L2E_); eA.y = fexp2((sA.y - m) * L2E_);
        eA.z = fexp2((sA.z - m) * L2E_); eA.w = fexp2((sA.w - m) * L2E_);
        eB.x = fexp2((sB.x - m) * L2E_); eB.y = fexp2((sB.y - m) * L2E_);
        eB.z = fexp2((sB.z - m) * L2E_); eB.w = fexp2((sB.w - m) * L2E_);
        float s = eA.x + eA.y + eA.z + eA.w + eB.x + eB.y + eB.z + eB.w;
#pragma unroll
        for (int mask = 1; mask < 64; mask <<= 1) s += __shfl_xor(s, mask);
        float inv = frcp(s);
        eA.x *= inv; eA.y *= inv; eA.z *= inv; eA.w *= inv;
        eB.x *= inv; eB.y *= inv; eB.z *= inv; eB.w *= inv;
        float4* op = (float4*)&out_attn[(b * TQ_ + q0 + w) * TK_ + lane * 8];
        op[0] = eA; op[1] = eB;
    }
}

// ------------------------------------------------------------- context ----
// One block: 16 q x 128 v, full K=512, reg-prefetch pipeline.
__global__ __launch_bounds__(256, 4) void context_kernel(
        const float* __restrict__ attn, const float* __restrict__ values,
        float* __restrict__ outc) {
    __shared__ float at[32][20];    // [kk][q]
    __shared__ float vt[32][132];   // [kk][v]

    const int tid = threadIdx.x;
    const int b   = blockIdx.y;
    const int q0  = (blockIdx.x >> 2) * 16;
    const int v0  = (blockIdx.x & 3) * 128;

    const int tx = tid & 31, ty = tid >> 5;
    const int v4 = tx * 4,   r2 = ty * 2;
    const int ar = tid >> 3, akq = (tid & 7) * 4;   // attn staging (tid<128)
    const int vk = tid >> 5;                        // values staging rows vk+8p

    const float* pAt = attn + (size_t)(b * TQ_ + q0 + ar) * TK_ + akq;
    const float* pV0 = values + (size_t)(b * TK_ + vk     ) * NV_ + v0 + v4;
    const float* pV1 = values + (size_t)(b * TK_ + vk +  8) * NV_ + v0 + v4;
    const float* pV2 = values + (size_t)(b * TK_ + vk + 16) * NV_ + v0 + v4;
    const float* pV3 = values + (size_t)(b * TK_ + vk + 24) * NV_ + v0 + v4;

    float4 af = {0.f,0.f,0.f,0.f};
    if (tid < 128) af = *(const float4*)pAt;
    float4 vf0 = *(const float4*)pV0;
    float4 vf1 = *(const float4*)pV1;
    float4 vf2 = *(const float4*)pV2;
    float4 vf3 = *(const float4*)pV3;

    float acc[2][4] = {{0.f,0.f,0.f,0.f},{0.f,0.f,0.f,0.f}};

    for (int c = 0; c < 16; ++c) {
        __syncthreads();
        if (tid < 128) {
            at[akq+0][ar] = af.x; at[akq+1][ar] = af.y;
            at[akq+2][ar] = af.z; at[akq+3][ar] = af.w;
        }
        *(float4*)&vt[vk     ][v4] = vf0;
        *(float4*)&vt[vk +  8][v4] = vf1;
        *(float4*)&vt[vk + 16][v4] = vf2;
        *(float4*)&vt[vk + 24][v4] = vf3;
        __syncthreads();
        if (c + 1 < 16) {
            pAt += 32; pV0 += 32 * NV_; pV1 += 32 * NV_;
            pV2 += 32 * NV_; pV3 += 32 * NV_;
            if (tid < 128) af = *(const float4*)pAt;
            vf0 = *(const float4*)pV0; vf1 = *(const float4*)pV1;
            vf2 = *(const float4*)pV2; vf3 = *(const float4*)pV3;
        }
#pragma unroll 8
        for (int kk = 0; kk < 32; ++kk) {
            float2 a = *(const float2*)&at[kk][r2];
            float4 v = *(const float4*)&vt[kk][v4];
            acc[0][0] = fmaf(a.x, v.x, acc[0][0]);
            acc[0][1] = fmaf(a.x, v.y, acc[0][1]);
            acc[0][2] = fmaf(a.x, v.z, acc[0][2]);
            acc[0][3] = fmaf(a.x, v.w, acc[0][3]);
            acc[1][0] = fmaf(a.y, v.x, acc[1][0]);
            acc[1][1] = fmaf(a.y, v.y, acc[1][1]);
            acc[1][2] = fmaf(a.y, v.z, acc[1][2]);
            acc[1][3] = fmaf(a.y, v.w, acc[1][3]);
        }
    }
    float4 o0 = {acc[0][0], acc[0][1], acc[0][2], acc[0][3]};
    float4 o1 = {acc[1][0], acc[1][1], acc[1][2], acc[1][3]};
    *(float4*)&outc[(size_t)(b * TQ_ + q0 + r2 + 0) * NV_ + v0 + v4] = o0;
    *(float4*)&outc[(size_t)(b * TQ_ + q0 + r2 + 1) * NV_ + v0 + v4] = o1;
}

// -------------------------------------------------------------- launch ----
extern "C" void kernel_launch(void* const* d_in, const int* in_sizes, int n_in,
                              void* d_out, int out_size, void* d_ws, size_t ws_size,
                              hipStream_t stream) {
    const float* query  = (const float*)d_in[0];
    const float* keys   = (const float*)d_in[1];
    const float* values = (const float*)d_in[2];
    const float* Wq     = (const float*)d_in[3];
    const float* bq     = (const float*)d_in[4];
    const float* Wk     = (const float*)d_in[5];
    const float* bk     = (const float*)d_in[6];
    const float* Wo     = (const float*)d_in[7];
    const float* bo     = (const float*)d_in[8];

    float* out_ctx  = (float*)d_out;                 // B*TQ*NV
    float* out_attn = out_ctx + B_ * TQ_ * NV_;      // B*TQ*TK
    float* qp   = (float*)d_ws;                      // NQR*H
    float* kpT  = qp + (size_t)NQR * H_;             // B*H*TK (transposed, *C2)
    float* psum = kpT + (size_t)B_ * H_ * TK_;       // 4*NROWS*H

    proj_kernel<<<dim3(NROWS / 16, 4), 256, 0, stream>>>(
        query, keys, Wq, Wk, psum, NIN_ / 4);
    reduce_kernel<<<NROWS / 16, 256, 0, stream>>>(psum, bq, bk, qp, kpT);
    scores_kernel<<<dim3(TQ_ / 2, B_), 256, 0, stream>>>(qp, kpT, Wo, bo, out_attn);
    context_kernel<<<dim3(32, B_), 256, 0, stream>>>(out_attn, values, out_ctx);
}